// Round 1
// baseline (325.895 us; speedup 1.0000x reference)
//
#include <hip/hip_runtime.h>
#include <math.h>

// Problem dims (fixed)
#define B_   128
#define L_   256
#define H_   128
#define H2_  256
#define VS_  256
#define TOK_ (B_ * L_)   // 32768

__device__ __forceinline__ float fma4(float4 a, float4 b, float acc) {
    acc = fmaf(a.x, b.x, acc);
    acc = fmaf(a.y, b.y, acc);
    acc = fmaf(a.z, b.z, acc);
    acc = fmaf(a.w, b.w, acc);
    return acc;
}

// LDS index swizzles (XOR row bits into the float4-column bits to spread banks)
#define HIDX(row, c4) ((row) * 32 + ((c4) ^ (((row) >> 2) & 7)))
#define WIDX(oc, k4)  ((oc) * 16 + ((k4) ^ (((oc) >> 2) & 15)))
#define YIDX(row, y4) ((row) * 16 + ((y4) ^ (((row) >> 2) & 15)))

// ---------------------------------------------------------------------------
// Kernel 1: fused  h = embed[seq];  f = relu(h@W1^T+b1)@W2^T+b2;
//                  x = h+f;  hln = LN(x)*gamma+beta;  K = hln@Wk^T
// 64 tokens per block, 256 threads, 64 KiB LDS.
// ---------------------------------------------------------------------------
__global__ __launch_bounds__(256, 2) void k_ffn(
    const int* __restrict__ seq, const float* __restrict__ embed,
    const float* __restrict__ W1, const float* __restrict__ b1,
    const float* __restrict__ W2, const float* __restrict__ b2,
    const float* __restrict__ gamma, const float* __restrict__ beta,
    const float* __restrict__ Wk, float* __restrict__ Kout)
{
    __shared__ float4 sh_h[64 * 32];  // 32 KiB: h tile, then x, then hln
    __shared__ float4 sh_w[64 * 16];  // 16 KiB: weight staging (64x64 f32)
    __shared__ float4 sh_y[64 * 16];  // 16 KiB: relu(y1) chunk (64x64 f32)

    const int tid  = threadIdx.x;
    const int tc   = tid & 15;   // 16 col-groups
    const int tr   = tid >> 4;   // 16 row-groups (4 token-rows each)
    const int tok0 = blockIdx.x * 64;

    const float4* embed4 = (const float4*)embed;
    const float4* W1_4   = (const float4*)W1;
    const float4* W2_4   = (const float4*)W2;
    const float4* Wk_4   = (const float4*)Wk;
    const float4* b1_4   = (const float4*)b1;
    const float4* b2_4   = (const float4*)b2;
    const float4* g_4    = (const float4*)gamma;
    const float4* be_4   = (const float4*)beta;

    // ---- gather h = embed[seq] ----
    #pragma unroll
    for (int f = tid; f < 2048; f += 256) {
        int row = f >> 5, c4 = f & 31;
        int idx = seq[tok0 + row];
        sh_h[HIDX(row, c4)] = embed4[idx * 32 + c4];
    }
    __syncthreads();

    float xacc[4][2][4];  // GEMM2 accum: [tok i][col-half xh][col j]
    #pragma unroll
    for (int i = 0; i < 4; ++i)
        #pragma unroll
        for (int xh = 0; xh < 2; ++xh)
            #pragma unroll
            for (int j = 0; j < 4; ++j) xacc[i][xh][j] = 0.f;

    for (int nt = 0; nt < 4; ++nt) {  // 4 chunks of 64 y1-columns
        float acc1[4][4];
        #pragma unroll
        for (int i = 0; i < 4; ++i)
            #pragma unroll
            for (int j = 0; j < 4; ++j) acc1[i][j] = 0.f;

        for (int kt = 0; kt < 2; ++kt) {  // K=128 in two 64 halves
            #pragma unroll
            for (int f = tid; f < 1024; f += 256) {
                int oc = f >> 4, k4 = f & 15;
                sh_w[WIDX(oc, k4)] = W1_4[(nt * 64 + oc) * 32 + kt * 16 + k4];
            }
            __syncthreads();
            #pragma unroll 4
            for (int k4i = 0; k4i < 16; ++k4i) {
                float4 a4[4], b4[4];
                #pragma unroll
                for (int i = 0; i < 4; ++i) a4[i] = sh_h[HIDX(tr * 4 + i, kt * 16 + k4i)];
                #pragma unroll
                for (int j = 0; j < 4; ++j) b4[j] = sh_w[WIDX(tc * 4 + j, k4i)];
                #pragma unroll
                for (int i = 0; i < 4; ++i)
                    #pragma unroll
                    for (int j = 0; j < 4; ++j) acc1[i][j] = fma4(a4[i], b4[j], acc1[i][j]);
            }
            __syncthreads();
        }
        // bias + relu -> sh_y
        {
            float4 bv = b1_4[nt * 16 + tc];
            #pragma unroll
            for (int i = 0; i < 4; ++i) {
                float4 y;
                y.x = fmaxf(acc1[i][0] + bv.x, 0.f);
                y.y = fmaxf(acc1[i][1] + bv.y, 0.f);
                y.z = fmaxf(acc1[i][2] + bv.z, 0.f);
                y.w = fmaxf(acc1[i][3] + bv.w, 0.f);
                sh_y[YIDX(tr * 4 + i, tc)] = y;
            }
        }
        __syncthreads();

        #pragma unroll
        for (int xh = 0; xh < 2; ++xh) {  // x-columns in two 64 halves
            #pragma unroll
            for (int f = tid; f < 1024; f += 256) {
                int oc = f >> 4, y4 = f & 15;
                sh_w[WIDX(oc, y4)] = W2_4[(xh * 64 + oc) * 64 + nt * 16 + y4];
            }
            __syncthreads();
            #pragma unroll 4
            for (int y4i = 0; y4i < 16; ++y4i) {
                float4 a4[4], b4[4];
                #pragma unroll
                for (int i = 0; i < 4; ++i) a4[i] = sh_y[YIDX(tr * 4 + i, y4i)];
                #pragma unroll
                for (int j = 0; j < 4; ++j) b4[j] = sh_w[WIDX(tc * 4 + j, y4i)];
                #pragma unroll
                for (int i = 0; i < 4; ++i)
                    #pragma unroll
                    for (int j = 0; j < 4; ++j) xacc[i][xh][j] = fma4(a4[i], b4[j], xacc[i][xh][j]);
            }
            __syncthreads();
        }
    }

    // ---- x = h + f + b2  (write back into sh_h) ----
    #pragma unroll
    for (int xh = 0; xh < 2; ++xh) {
        float4 bv = b2_4[xh * 16 + tc];
        int c4 = xh * 16 + tc;
        #pragma unroll
        for (int i = 0; i < 4; ++i) {
            float4 h4 = sh_h[HIDX(tr * 4 + i, c4)];
            h4.x += xacc[i][xh][0] + bv.x;
            h4.y += xacc[i][xh][1] + bv.y;
            h4.z += xacc[i][xh][2] + bv.z;
            h4.w += xacc[i][xh][3] + bv.w;
            sh_h[HIDX(tr * 4 + i, c4)] = h4;
        }
    }
    __syncthreads();

    // ---- LayerNorm over 128 cols, 4 threads per row ----
    {
        int row = tid >> 2, q = tid & 3;
        float s = 0.f, s2 = 0.f;
        #pragma unroll
        for (int u = 0; u < 8; ++u) {
            float4 v = sh_h[HIDX(row, q * 8 + u)];
            s  += v.x + v.y + v.z + v.w;
            s2 += v.x * v.x + v.y * v.y + v.z * v.z + v.w * v.w;
        }
        s  += __shfl_xor(s, 1);  s  += __shfl_xor(s, 2);
        s2 += __shfl_xor(s2, 1); s2 += __shfl_xor(s2, 2);
        float mu   = s * (1.f / 128.f);
        float var  = s2 * (1.f / 128.f) - mu * mu;
        float rstd = 1.f / sqrtf(var + 1e-5f);
        #pragma unroll
        for (int u = 0; u < 8; ++u) {
            int c4 = q * 8 + u;
            float4 v  = sh_h[HIDX(row, c4)];
            float4 gv = g_4[c4], bev = be_4[c4];
            v.x = (v.x - mu) * rstd * gv.x + bev.x;
            v.y = (v.y - mu) * rstd * gv.y + bev.y;
            v.z = (v.z - mu) * rstd * gv.z + bev.z;
            v.w = (v.w - mu) * rstd * gv.w + bev.w;
            sh_h[HIDX(row, c4)] = v;
        }
    }
    __syncthreads();

    // ---- K = hln @ Wk^T ----
    for (int ch = 0; ch < 2; ++ch) {  // output-col halves
        float acc[4][4];
        #pragma unroll
        for (int i = 0; i < 4; ++i)
            #pragma unroll
            for (int j = 0; j < 4; ++j) acc[i][j] = 0.f;

        for (int kt = 0; kt < 2; ++kt) {
            #pragma unroll
            for (int f = tid; f < 1024; f += 256) {
                int oc = f >> 4, k4 = f & 15;
                sh_w[WIDX(oc, k4)] = Wk_4[(ch * 64 + oc) * 32 + kt * 16 + k4];
            }
            __syncthreads();
            #pragma unroll 4
            for (int k4i = 0; k4i < 16; ++k4i) {
                float4 a4[4], b4[4];
                #pragma unroll
                for (int i = 0; i < 4; ++i) a4[i] = sh_h[HIDX(tr * 4 + i, kt * 16 + k4i)];
                #pragma unroll
                for (int j = 0; j < 4; ++j) b4[j] = sh_w[WIDX(tc * 4 + j, k4i)];
                #pragma unroll
                for (int i = 0; i < 4; ++i)
                    #pragma unroll
                    for (int j = 0; j < 4; ++j) acc[i][j] = fma4(a4[i], b4[j], acc[i][j]);
            }
            __syncthreads();
        }
        #pragma unroll
        for (int i = 0; i < 4; ++i) {
            float4 o = make_float4(acc[i][0], acc[i][1], acc[i][2], acc[i][3]);
            ((float4*)Kout)[(tok0 + tr * 4 + i) * 32 + ch * 16 + tc] = o;
        }
    }
}

// ---------------------------------------------------------------------------
// Kernel 2: sequential gated delta-rule scan. One block per batch.
// M (128x128 f32) lives in registers: thread (rg,cg) owns rows rg*4..+4,
// cols cg*16..+16.  255 steps, 2 barriers/step, k(t+1) prefetched.
// ---------------------------------------------------------------------------
__global__ __launch_bounds__(256) void k_scan(
    const float* __restrict__ Kbuf, float* __restrict__ readout)
{
    __shared__ float4 sh_k[2][32];
    __shared__ float  sh_red[4];

    const int tid = threadIdx.x;
    const int b   = blockIdx.x;
    const int cg  = tid & 7;    // 8 col-groups (16 cols each)
    const int rg  = tid >> 3;   // 32 row-groups (4 rows each)
    const float4* K4 = (const float4*)Kbuf;

    float m[4][16];
    #pragma unroll
    for (int i = 0; i < 4; ++i)
        #pragma unroll
        for (int j = 0; j < 16; ++j) m[i][j] = 0.f;

    if (tid < 32) sh_k[0][tid] = K4[(b * 256 + 0) * 32 + tid];
    __syncthreads();

    for (int t = 0; t < 255; ++t) {
        float4 kpre;
        if (tid < 32) kpre = K4[(b * 256 + t + 1) * 32 + tid];  // prefetch next k

        const float4* kcur = sh_k[t & 1];
        float kc[16], kr[4];
        #pragma unroll
        for (int u = 0; u < 4; ++u) {
            float4 v = kcur[cg * 4 + u];
            kc[u * 4 + 0] = v.x; kc[u * 4 + 1] = v.y;
            kc[u * 4 + 2] = v.z; kc[u * 4 + 3] = v.w;
        }
        { float4 v = kcur[rg]; kr[0] = v.x; kr[1] = v.y; kr[2] = v.z; kr[3] = v.w; }

        // ||k||^2 (butterfly over the 8 col-groups; identical on all threads)
        float n2 = 0.f;
        #pragma unroll
        for (int j = 0; j < 16; ++j) n2 = fmaf(kc[j], kc[j], n2);
        n2 += __shfl_xor(n2, 1); n2 += __shfl_xor(n2, 2); n2 += __shfl_xor(n2, 4);

        float rinv = 1.f / fmaxf(sqrtf(n2), 1e-12f);
        float kn[16];
        #pragma unroll
        for (int j = 0; j < 16; ++j) kn[j] = kc[j] * rinv;

        // vp = M @ kn  (partial per thread, reduce across col-groups)
        float p[4] = {0.f, 0.f, 0.f, 0.f};
        #pragma unroll
        for (int i = 0; i < 4; ++i)
            #pragma unroll
            for (int j = 0; j < 16; ++j) p[i] = fmaf(m[i][j], kn[j], p[i]);
        #pragma unroll
        for (int i = 0; i < 4; ++i) {
            p[i] += __shfl_xor(p[i], 1);
            p[i] += __shfl_xor(p[i], 2);
            p[i] += __shfl_xor(p[i], 4);
        }

        float err[4];
        #pragma unroll
        for (int i = 0; i < 4; ++i) err[i] = kr[i] - p[i];

        // ||err||^2: per-octet value, sum distinct row-groups across wave
        float el = 0.f;
        #pragma unroll
        for (int i = 0; i < 4; ++i) el = fmaf(err[i], err[i], el);
        el += __shfl_xor(el, 8); el += __shfl_xor(el, 16); el += __shfl_xor(el, 32);

        if ((tid & 63) == 0) sh_red[tid >> 6] = el;
        __syncthreads();                                   // barrier A
        float e2 = sh_red[0] + sh_red[1] + sh_red[2] + sh_red[3];

        if (tid < 32) sh_k[(t + 1) & 1][tid] = kpre;       // land prefetch

        if (e2 >= 0.16f * n2) {                            // block-uniform gate
            #pragma unroll
            for (int i = 0; i < 4; ++i)
                #pragma unroll
                for (int j = 0; j < 16; ++j) m[i][j] = fmaf(err[i], kn[j], m[i][j]);
        }
        __syncthreads();                                   // barrier B
    }

    // read = M @ q  (q = K[b, 255], already in sh_k[1], unnormalized)
    {
        const float4* kcur = sh_k[1];
        float qv[16];
        #pragma unroll
        for (int u = 0; u < 4; ++u) {
            float4 v = kcur[cg * 4 + u];
            qv[u * 4 + 0] = v.x; qv[u * 4 + 1] = v.y;
            qv[u * 4 + 2] = v.z; qv[u * 4 + 3] = v.w;
        }
        float p[4] = {0.f, 0.f, 0.f, 0.f};
        #pragma unroll
        for (int i = 0; i < 4; ++i)
            #pragma unroll
            for (int j = 0; j < 16; ++j) p[i] = fmaf(m[i][j], qv[j], p[i]);
        #pragma unroll
        for (int i = 0; i < 4; ++i) {
            p[i] += __shfl_xor(p[i], 1);
            p[i] += __shfl_xor(p[i], 2);
            p[i] += __shfl_xor(p[i], 4);
        }
        if (cg == 0)
            ((float4*)readout)[b * 32 + rg] = make_float4(p[0], p[1], p[2], p[3]);
    }
}

// ---------------------------------------------------------------------------
// Kernel 3: out = (read @ Wr^T + br) @ Wo^T + bo.  One block per batch.
// ---------------------------------------------------------------------------
__global__ __launch_bounds__(256) void k_out(
    const float* __restrict__ readout,
    const float* __restrict__ Wr, const float* __restrict__ br,
    const float* __restrict__ Wo, const float* __restrict__ bo,
    float* __restrict__ out)
{
    __shared__ float sh_rd[128];
    __shared__ float sh_r2[128];
    const int b = blockIdx.x, tid = threadIdx.x;

    if (tid < 32) ((float4*)sh_rd)[tid] = ((const float4*)readout)[b * 32 + tid];
    __syncthreads();

    {   // r2[i] = br[i] + read . Wr[i,:]   (2 threads per output)
        int i = tid >> 1, h = tid & 1;
        const float4* Wr4 = (const float4*)Wr;
        const float4* rd4 = (const float4*)sh_rd;
        float s = 0.f;
        #pragma unroll
        for (int u = 0; u < 16; ++u) s = fma4(rd4[h * 16 + u], Wr4[i * 32 + h * 16 + u], s);
        s += __shfl_xor(s, 1);
        if (h == 0) sh_r2[i] = s + br[i];
    }
    __syncthreads();

    {   // out[v] = bo[v] + r2 . Wo[v,:]
        const float4* Wo4 = (const float4*)Wo;
        const float4* r24 = (const float4*)sh_r2;
        float acc = bo[tid];
        #pragma unroll
        for (int u = 0; u < 32; ++u) acc = fma4(r24[u], Wo4[tid * 32 + u], acc);
        out[b * 256 + tid] = acc;
    }
}

// ---------------------------------------------------------------------------
extern "C" void kernel_launch(void* const* d_in, const int* in_sizes, int n_in,
                              void* d_out, int out_size, void* d_ws, size_t ws_size,
                              hipStream_t stream) {
    const int*   seq   = (const int*)  d_in[0];
    const float* embed = (const float*)d_in[1];
    const float* W1    = (const float*)d_in[2];
    const float* b1    = (const float*)d_in[3];
    const float* W2    = (const float*)d_in[4];
    const float* b2    = (const float*)d_in[5];
    const float* gamma = (const float*)d_in[6];
    const float* beta  = (const float*)d_in[7];
    const float* Wk    = (const float*)d_in[8];
    const float* Wr    = (const float*)d_in[9];
    const float* br    = (const float*)d_in[10];
    const float* Wo    = (const float*)d_in[11];
    const float* bo    = (const float*)d_in[12];

    float* Kbuf    = (float*)d_ws;                    // 32768 * 128 f32 = 16 MiB
    float* readout = Kbuf + (size_t)TOK_ * H_;        // 128 * 128 f32
    float* out     = (float*)d_out;

    k_ffn <<<TOK_ / 64, 256, 0, stream>>>(seq, embed, W1, b1, W2, b2, gamma, beta, Wk, Kbuf);
    k_scan<<<B_,       256, 0, stream>>>(Kbuf, readout);
    k_out <<<B_,       256, 0, stream>>>(readout, Wr, br, Wo, bo, out);
}